// Round 6
// baseline (2550.924 us; speedup 1.0000x reference)
//
#include <hip/hip_runtime.h>
#include <cstddef>

typedef _Float16 half8v __attribute__((ext_vector_type(8)));
typedef _Float16 half4v __attribute__((ext_vector_type(4)));
typedef float f32x4 __attribute__((ext_vector_type(4)));

#define MFMA32(A, B, C) __builtin_amdgcn_mfma_f32_16x16x32_f16(A, B, C, 0, 0, 0)
#define MFMA16(A, B, C) __builtin_amdgcn_mfma_f32_16x16x16f16(A, B, C, 0, 0, 0)

// ============ kw2: W2 -> f16 copy (row-major 256x128) ============
__global__ void kw2_kernel(const float* __restrict__ W2, _Float16* __restrict__ w2h) {
  int i = blockIdx.x * 256 + threadIdx.x;
  w2h[i] = (_Float16)W2[i];
}

// ============ kprep1: per (b,t): A, chol (in-wave), Ainv, klc, pf-chunk(f16), c' ============
__global__ void kprep1_kernel(const float* __restrict__ Kg,
                              const float* __restrict__ kg,
                              const float* __restrict__ ug,
                              const float* __restrict__ Qd,
                              const float* __restrict__ Q0d,
                              float* __restrict__ Ainv,
                              float* __restrict__ klc,
                              _Float16* __restrict__ pfb,
                              float* __restrict__ cgp) {
  int tid = threadIdx.x;
  int wv = tid >> 6, ln = tid & 63;
  size_t bt = (size_t)blockIdx.x * 4 + wv;
  int t = (int)(bt & 255);
  __shared__ float Ks[4][128][20];   // later reused as Ps[l][r]
  __shared__ float qs[4][128];
  __shared__ float vvs[4][128];
  __shared__ float Asm[4][16][20];
  __shared__ float LiL[4][16][20];
  __shared__ float AiS[4][16][20];
  __shared__ float yps[4][4][16];
  __shared__ float yvs[4][16];

  const float* kp = Kg + bt * 2048;
  for (int i = ln; i < 2048; i += 64) Ks[wv][i >> 4][i & 15] = kp[i];
  for (int l = ln; l < 128; l += 64) {
    float q = (t == 0) ? Q0d[l] : Qd[l];
    qs[wv][l] = q;
    float v = Qd[l] * kg[bt * 128 + l];
    if (t > 0 && l < 64) v += ug[bt * 64 + l];
    vvs[wv][l] = v;
  }
  __syncthreads();
  {
    int r = ln & 15, c0 = (ln >> 4) << 2;
    float a0 = 0, a1 = 0, a2 = 0, a3 = 0;
    for (int l = 0; l < 128; ++l) {
      float kq = Ks[wv][l][r] * qs[wv][l];
      const float* row = &Ks[wv][l][c0];
      a0 += kq * row[0]; a1 += kq * row[1]; a2 += kq * row[2]; a3 += kq * row[3];
    }
    Asm[wv][r][c0 + 0] = a0 + ((r == c0 + 0) ? 1.f : 0.f);
    Asm[wv][r][c0 + 1] = a1 + ((r == c0 + 1) ? 1.f : 0.f);
    Asm[wv][r][c0 + 2] = a2 + ((r == c0 + 2) ? 1.f : 0.f);
    Asm[wv][r][c0 + 3] = a3 + ((r == c0 + 3) ? 1.f : 0.f);
  }
  {
    int r = ln & 15, seg = ln >> 4;
    float s = 0.f;
    for (int l = seg * 32; l < seg * 32 + 32; ++l) s += Ks[wv][l][r] * vvs[wv][l];
    yps[wv][seg][r] = s;
  }
  __syncthreads();
  if (ln < 16) {
    int i = ln;
    float ar[16], Lr[16];
#pragma unroll
    for (int j = 0; j < 16; ++j) ar[j] = Asm[wv][i][j];
    float ld = 0.f;
#pragma unroll
    for (int j = 0; j < 16; ++j) {
      float ajj = __shfl(ar[j], j, 64);
      float d = sqrtf(ajj);
      ld += __logf(d);
      float li = ar[j] / d;
      li = (i >= j) ? li : 0.f;
      Lr[j] = li;
#pragma unroll
      for (int k2 = j; k2 < 16; ++k2) {
        float lk = __shfl(li, k2, 64);
        ar[k2] -= li * lk;
      }
    }
    int cc = i;
    float Lic[16];
#pragma unroll
    for (int ii = 0; ii < 16; ++ii) {
      float s = (ii == cc) ? 1.f : 0.f;
#pragma unroll
      for (int p = 0; p < 16; ++p) {
        if (p < ii) {
          float Lip = __shfl(Lr[p], ii, 64);
          s -= Lip * Lic[p];
        }
      }
      float dii = __shfl(Lr[ii], ii, 64);
      float v = s / dii;
      Lic[ii] = (ii >= cc) ? v : 0.f;
    }
    float tr = 0.f;
#pragma unroll
    for (int ii = 0; ii < 16; ++ii) { tr += Lic[ii] * Lic[ii]; LiL[wv][cc][ii] = Lic[ii]; }
    tr += __shfl_xor(tr, 1); tr += __shfl_xor(tr, 2);
    tr += __shfl_xor(tr, 4); tr += __shfl_xor(tr, 8);
    if (cc == 0) klc[bt] = 0.5f * (tr - 16.f + 2.f * ld);
    yvs[wv][cc] = yps[wv][0][cc] + yps[wv][1][cc] + yps[wv][2][cc] + yps[wv][3][cc];
  }
  __syncthreads();
  {
    int r = ln & 15, c0 = (ln >> 4) << 2;
    float a0 = 0, a1 = 0, a2 = 0, a3 = 0;
    for (int ii = 0; ii < 16; ++ii) {
      float lir = LiL[wv][r][ii];
      a0 += lir * LiL[wv][c0 + 0][ii];
      a1 += lir * LiL[wv][c0 + 1][ii];
      a2 += lir * LiL[wv][c0 + 2][ii];
      a3 += lir * LiL[wv][c0 + 3][ii];
    }
    AiS[wv][r][c0 + 0] = a0; AiS[wv][r][c0 + 1] = a1;
    AiS[wv][r][c0 + 2] = a2; AiS[wv][r][c0 + 3] = a3;
    f32x4 av = {a0, a1, a2, a3};
    *(f32x4*)&Ainv[bt * 256 + r * 16 + c0] = av;
  }
  __syncthreads();
  // P = q*(K Ainv); c' = q*k - P.y2; store P into Ks (reuse) for fragment gather
  {
#pragma unroll
    for (int li = 0; li < 2; ++li) {
      int l = ln * 2 + li;
      f32x4 acc0 = {0,0,0,0}, acc1v = {0,0,0,0}, acc2v = {0,0,0,0}, acc3v = {0,0,0,0};
      for (int j = 0; j < 16; ++j) {
        float kj = Ks[wv][l][j];
        acc0  += kj * *(const f32x4*)&AiS[wv][j][0];
        acc1v += kj * *(const f32x4*)&AiS[wv][j][4];
        acc2v += kj * *(const f32x4*)&AiS[wv][j][8];
        acc3v += kj * *(const f32x4*)&AiS[wv][j][12];
      }
      float ql = qs[wv][l];
      float cp = ql * kg[bt * 128 + l];
      float pv[16];
#pragma unroll
      for (int e = 0; e < 4; ++e) {
        pv[e] = ql * acc0[e]; pv[4 + e] = ql * acc1v[e];
        pv[8 + e] = ql * acc2v[e]; pv[12 + e] = ql * acc3v[e];
      }
#pragma unroll
      for (int r = 0; r < 16; ++r) cp -= pv[r] * yvs[wv][r];
      cgp[bt * 128 + l] = cp;
#pragma unroll
      for (int r = 0; r < 16; ++r) Ks[wv][l][r] = pv[r];
    }
  }
  __syncthreads();
  {
    int gp = ln >> 4, cp = ln & 15;
#pragma unroll
    for (int ci = 0; ci < 4; ++ci) {
      half8v o;
#pragma unroll
      for (int mt = 0; mt < 2; ++mt)
#pragma unroll
        for (int j = 0; j < 4; ++j)
          o[mt * 4 + j] = (_Float16)Ks[wv][ci * 32 + mt * 16 + cp][gp * 4 + j];
      *(half8v*)(pfb + bt * 2048 + (size_t)(ci * 64 + ln) * 8) = o;
    }
  }
}

// ============ kprepR: R = (W2 K) fragments + K f16 fragments ============
__global__ void kprepR_kernel(const float* __restrict__ Kg,
                              const _Float16* __restrict__ w2h,
                              _Float16* __restrict__ rfb,
                              _Float16* __restrict__ kab) {
  int tid = threadIdx.x;
  int wv = tid >> 6, ln = tid & 63;
  int g = ln >> 4, c = ln & 15;
  __shared__ _Float16 Kh[128][20];
  __shared__ _Float16 Rh[16][264];
  for (int it = 0; it < 4; ++it) {
    size_t bt = (size_t)blockIdx.x * 4 + it;
    const float* kp = Kg + bt * 2048;
    for (int i = tid; i < 2048; i += 256) Kh[i >> 4][i & 15] = (_Float16)kp[i];
    __syncthreads();
    half8v kA[4];
#pragma unroll
    for (int kt = 0; kt < 4; ++kt)
#pragma unroll
      for (int j = 0; j < 8; ++j) kA[kt][j] = Kh[kt * 32 + g * 8 + j][c];
#pragma unroll
    for (int i = 0; i < 4; ++i) {
      int tile = wv * 4 + i;
      f32x4 acc = {0, 0, 0, 0};
#pragma unroll
      for (int kt = 0; kt < 4; ++kt) {
        half8v bf = *(const half8v*)&w2h[(size_t)(tile * 16 + c) * 128 + kt * 32 + g * 8];
        acc = MFMA32(kA[kt], bf, acc);
      }
#pragma unroll
      for (int r = 0; r < 4; ++r) Rh[g * 4 + r][tile * 16 + c] = (_Float16)acc[r];
    }
    __syncthreads();
    half8v r0, r1;
#pragma unroll
    for (int mt = 0; mt < 4; ++mt)
#pragma unroll
      for (int j = 0; j < 4; ++j) {
        _Float16 v = Rh[c][wv * 64 + mt * 16 + g * 4 + j];
        if (mt < 2) r0[mt * 4 + j] = v; else r1[(mt - 2) * 4 + j] = v;
      }
    *(half8v*)(rfb + bt * 4096 + (size_t)tid * 16) = r0;
    *(half8v*)(rfb + bt * 4096 + (size_t)tid * 16 + 8) = r1;
    if (kab) {
      half8v ko;
#pragma unroll
      for (int kt = 0; kt < 2; ++kt)
#pragma unroll
        for (int j = 0; j < 4; ++j) ko[kt * 4 + j] = Kh[wv * 32 + kt * 16 + g * 4 + j][c];
      *(half8v*)(kab + bt * 2048 + (size_t)tid * 8) = ko;
    }
    __syncthreads();
  }
}

// ============ kc: per (t,b): z_p out + zpc = z_p - K Ainv (K^T z_p + ew) ============
__global__ void kc_kernel(const float* __restrict__ Kg,
                          const float* __restrict__ epsz,
                          const float* __restrict__ epsw,
                          const float* __restrict__ Qd,
                          const float* __restrict__ Q0d,
                          const float* __restrict__ Ainv,
                          float* __restrict__ out_zf,
                          float* __restrict__ out_zp,
                          float* __restrict__ zpcb,
                          int zw, int wzp) {
  int idx = blockIdx.x;
  int t = idx >> 6, b = idx & 63;
  int bt = b * 256 + t;
  __shared__ float Ks[128][16];
  __shared__ float Ai[16][16];
  __shared__ float zp[16][129];
  __shared__ float hh[16][17];
  __shared__ float ww[16][17];
  __shared__ float sq[128];
  const float* kp = Kg + (size_t)bt * 2048;
  for (int i = threadIdx.x; i < 2048; i += 256) ((float*)Ks)[i] = kp[i];
  ((float*)Ai)[threadIdx.x] = Ainv[(size_t)bt * 256 + threadIdx.x];
  const float* q = (t == 0) ? Q0d : Qd;
  if (threadIdx.x < 128) sq[threadIdx.x] = sqrtf(q[threadIdx.x]);
  __syncthreads();
  for (int i = threadIdx.x; i < 2048; i += 256) {
    int s = i >> 7, l = i & 127;
    float v = sq[l] * epsz[(((size_t)t * 16 + s) * 64 + b) * 128 + l];
    zp[s][l] = v;
    if (wzp) out_zp[(((size_t)s * 64 + b) * 256 + t) * 128 + l] = v;
  }
  __syncthreads();
  {
    int s = threadIdx.x >> 4, r = threadIdx.x & 15;
    float acc = epsw[(((size_t)t * 16 + s) * 64 + b) * 16 + r];
    for (int l = 0; l < 128; ++l) acc += Ks[l][r] * zp[s][l];
    hh[s][r] = acc;
  }
  __syncthreads();
  {
    int s = threadIdx.x >> 4, r = threadIdx.x & 15;
    float acc = 0.f;
    for (int j = 0; j < 16; ++j) acc += Ai[r][j] * hh[s][j];
    ww[s][r] = acc;
  }
  __syncthreads();
  for (int i = threadIdx.x; i < 2048; i += 256) {
    int s = i >> 7, l = i & 127;
    float acc = 0.f;
    for (int r = 0; r < 16; ++r) acc += Ks[l][r] * ww[s][r];
    float v = zp[s][l] - acc;
    if (zw) zpcb[(size_t)bt * 2048 + i] = v;
    else out_zf[(((size_t)s * 64 + b) * 256 + t) * 128 + l] = v;
  }
}

// ============ kzp: rebuild out_zp after kscan (rf lived in out_zp) ============
__global__ void kzp_kernel(const float* __restrict__ epsz,
                           const float* __restrict__ Qd,
                           const float* __restrict__ Q0d,
                           float* __restrict__ out_zp) {
  for (size_t i = (size_t)blockIdx.x * blockDim.x + threadIdx.x; i < (size_t)33554432;
       i += (size_t)gridDim.x * blockDim.x) {
    int l = (int)(i & 127);
    int t = (int)((i >> 7) & 255);
    int sb = (int)(i >> 15);
    int s = sb >> 6, b = sb & 63;
    float q = (t == 0) ? Q0d[l] : Qd[l];
    out_zp[i] = sqrtf(q) * epsz[(((size_t)t * 16 + s) * 64 + b) * 128 + l];
  }
}

// raw barrier: LDS-only drain, global loads/stores stay in flight
#define BAR() asm volatile("s_waitcnt lgkmcnt(0)\n\ts_barrier" ::: "memory")

// ============ kscan: 512 threads = TWO independent b-chains (2 waves/SIMD) ============
// __launch_bounds__(512, 1): do NOT cap VGPRs — weights alone need 128; the
// kernel needs ~208 and 2 waves/SIMD fit naturally at <=256 (round-5 lesson:
// (512,2) capped to 128 VGPR -> spill -> 3x regression).
template <bool PK, bool ZW>
__launch_bounds__(512, 1)
__global__ void kscan_kernel(const float* __restrict__ ug,
                             const float* __restrict__ Kg,
                             const float* __restrict__ W1,
                             const float* __restrict__ W2,
                             const float* __restrict__ m_init,
                             const float* __restrict__ Qd,
                             const float* __restrict__ Q0d,
                             const _Float16* __restrict__ pfb,
                             const float* __restrict__ cgp,
                             const _Float16* __restrict__ rfb,
                             const _Float16* __restrict__ kab,
                             const float* __restrict__ zpcb,
                             const float* __restrict__ klcp,
                             float* __restrict__ out_zf,
                             float* __restrict__ out_mf,
                             float* __restrict__ out_kl) {
  const int tid = threadIdx.x;
  const int ch = tid >> 8;        // chain within WG
  const int ct = tid & 255;       // thread within chain
  const int wvc = ct >> 6;        // dim-split wave within chain
  const int ln = tid & 63;
  const int g = ln >> 4;
  const int c = ln & 15;
  const int b = blockIdx.x * 2 + ch;

  __shared__ __align__(16) _Float16 svh[2][2048];  // z (f16), per chain
  __shared__ __align__(16) _Float16 hb[2][4096];   // tanh, per chain
  __shared__ float h2p[2][4][320];
  __shared__ float qpp[2][2][64];

  _Float16* svhc = svh[ch];
  _Float16* hbc = hb[ch];
  float (*h2pc)[320] = h2p[ch];
  float (*qppc)[64] = qpp[ch];

  half8v w1f[4][4];
#pragma unroll
  for (int mt = 0; mt < 4; ++mt)
#pragma unroll
    for (int kt = 0; kt < 4; ++kt) {
      half8v v;
#pragma unroll
      for (int j = 0; j < 8; ++j)
        v[j] = (_Float16)W1[(size_t)(kt * 32 + g * 8 + j) * 256 + (wvc * 64 + mt * 16 + c)];
      w1f[mt][kt] = v;
    }
  half8v w2f[2][8];
#pragma unroll
  for (int mt = 0; mt < 2; ++mt)
#pragma unroll
    for (int kt = 0; kt < 8; ++kt) {
      half8v v;
#pragma unroll
      for (int j = 0; j < 8; ++j)
        v[j] = (_Float16)W2[(size_t)(kt * 32 + g * 8 + j) * 128 + (wvc * 32 + mt * 16 + c)];
      w2f[mt][kt] = v;
    }

  f32x4 qiv[2], qiv0[2];
#pragma unroll
  for (int mt = 0; mt < 2; ++mt) {
    f32x4 q = *(const f32x4*)&Qd[wvc * 32 + mt * 16 + g * 4];
    f32x4 q0 = *(const f32x4*)&Q0d[wvc * 32 + mt * 16 + g * 4];
#pragma unroll
    for (int r = 0; r < 4; ++r) { qiv[mt][r] = 1.f / q[r]; qiv0[mt][r] = 1.f / q0[r]; }
  }

  f32x4 zreg[2];

  half8v pfx0, pfx1, kax0 = {}, kax1 = {}, rfa0, rfa1, rfc0, rfc1;
  float kf0[8], kf1[8];
  f32x4 zq0[2], zq1[2], cv0[2], cv1[2];
  f32x4 ur0[2] = {}, ur1[2] = {};
  float kv0 = 0.f, kv1 = 0.f;

  const char* pf_p = (const char*)pfb + (size_t)b * 256 * 4096 + (size_t)ct * 16;
  const char* ka_p = PK ? (const char*)kab + (size_t)b * 256 * 4096 + (size_t)ct * 16
                        : (const char*)pfb;
  const char* K_p = (const char*)Kg + (size_t)b * 256 * 8192 + (size_t)((wvc * 32 + g * 4) * 16 + c) * 4;
  const char* rf_p = (const char*)rfb + (size_t)b * 256 * 8192 + (size_t)ct * 32;
  const char* zq_p = ZW ? (const char*)zpcb + (size_t)b * 256 * 8192 + (size_t)(c * 128 + wvc * 32 + g * 4) * 4
                        : (const char*)out_zf + ((((size_t)c * 64 + b) * 256) * 128 + wvc * 32 + g * 4) * 4;
  const size_t zq_str = ZW ? 8192 : 512;
  const char* cv_p = (const char*)cgp + (size_t)b * 256 * 512 + (size_t)(wvc * 32 + g * 4) * 4;
  const char* ur_p = (const char*)ug + (size_t)b * 256 * 256 + (size_t)(wvc * 32 + g * 4) * 4;
  const char* kl_p = (const char*)klcp + (size_t)b * 256 * 4;
  char* zf_p = (char*)out_zf + ((((size_t)c * 64 + b) * 256) * 128 + wvc * 32 + g * 4) * 4;
  char* mf_p = (char*)out_mf + ((size_t)b * 256 * 128 + wvc * 32 + g * 4) * 4;

#define STAGE(BI) do { \
    pfx##BI = *(const half8v*)pf_p; pf_p += 4096; \
    if constexpr (PK) { kax##BI = *(const half8v*)ka_p; ka_p += 4096; } \
    else { _Pragma("unroll") for (int kt_ = 0; kt_ < 2; ++kt_) \
             _Pragma("unroll") for (int j_ = 0; j_ < 4; ++j_) \
               kf##BI[kt_ * 4 + j_] = *(const float*)(K_p + kt_ * 1024 + j_ * 64); \
           K_p += 8192; } \
    rfa##BI = *(const half8v*)rf_p; rfc##BI = *(const half8v*)(rf_p + 16); rf_p += 8192; \
    zq##BI[0] = *(const f32x4*)zq_p; zq##BI[1] = *(const f32x4*)(zq_p + 64); zq_p += zq_str; \
    cv##BI[0] = *(const f32x4*)cv_p; cv##BI[1] = *(const f32x4*)(cv_p + 64); cv_p += 512; \
    if (wvc < 2) { ur##BI[0] = *(const f32x4*)ur_p; ur##BI[1] = *(const f32x4*)(ur_p + 64); } \
    ur_p += 256; \
    kv##BI = *(const float*)kl_p; kl_p += 4; \
  } while (0)

#define KAH(BI, KT, DST) do { \
    if constexpr (PK) { _Pragma("unroll") for (int j_ = 0; j_ < 4; ++j_) DST[j_] = kax##BI[(KT) * 4 + j_]; } \
    else { _Pragma("unroll") for (int j_ = 0; j_ < 4; ++j_) DST[j_] = (_Float16)kf##BI[(KT) * 4 + j_]; } \
  } while (0)

#define PHASE_A(BI) do { \
    half4v zbh_[2], zbl_[2]; \
    _Pragma("unroll") for (int kt = 0; kt < 2; ++kt) \
      _Pragma("unroll") for (int j = 0; j < 4; ++j) { \
        float x_ = zreg[kt][j]; _Float16 h_ = (_Float16)x_; \
        zbh_[kt][j] = h_; zbl_[kt][j] = (_Float16)(x_ - (float)h_); } \
    half8v zh8_[4]; \
    _Pragma("unroll") for (int kt = 0; kt < 4; ++kt) { \
      int row_ = kt * 4 + g; \
      int idx_ = row_ * 128 + (((c + row_) & 15) << 3); \
      zh8_[kt] = *(const half8v*)&svhc[idx_]; } \
    f32x4 a1h_[4]; \
    _Pragma("unroll") for (int mt = 0; mt < 4; ++mt) a1h_[mt] = (f32x4){0,0,0,0}; \
    _Pragma("unroll") for (int kt = 0; kt < 4; ++kt) \
      _Pragma("unroll") for (int mt = 0; mt < 4; ++mt) \
        a1h_[mt] = MFMA32(w1f[mt][kt], zh8_[kt], a1h_[mt]); \
    half4v th_[4]; \
    _Pragma("unroll") for (int mt = 0; mt < 4; ++mt) { \
      _Pragma("unroll") for (int r = 0; r < 4; ++r) { \
        float x_ = a1h_[mt][r]; \
        float e_ = __expf(2.f * x_); \
        th_[mt][r] = (_Float16)(1.f - 2.f / (e_ + 1.f)); } \
      int row_ = wvc * 8 + mt * 2 + (g >> 1); \
      *(half4v*)&hbc[row_ * 128 + (((c + row_) & 15) << 3) + ((g & 1) << 2)] = th_[mt]; } \
    half4v ka0_, ka1_; KAH(BI, 0, ka0_); KAH(BI, 1, ka1_); \
    f32x4 hz_ = {0, 0, 0, 0}; \
    hz_ = MFMA16(ka0_, zbh_[0], hz_); hz_ = MFMA16(ka1_, zbh_[1], hz_); \
    hz_ = MFMA16(ka0_, zbl_[0], hz_); hz_ = MFMA16(ka1_, zbl_[1], hz_); \
    f32x4 hr_ = {0, 0, 0, 0}; \
    _Pragma("unroll") for (int mt = 0; mt < 4; ++mt) { \
      half4v rr_; \
      _Pragma("unroll") for (int j = 0; j < 4; ++j) \
        rr_[j] = (mt < 2) ? rfa##BI[mt * 4 + j] : rfc##BI[(mt - 2) * 4 + j]; \
      hr_ = MFMA16(rr_, th_[mt], hr_); } \
    *(f32x4*)&h2pc[wvc][c * 20 + g * 4] = hz_ + hr_; \
  } while (0)

#define EPILOG(BI, QIV, MV) do { \
    f32x4 h2v_ = *(const f32x4*)&h2pc[0][c * 20 + g * 4]; \
    h2v_ += *(const f32x4*)&h2pc[1][c * 20 + g * 4]; \
    h2v_ += *(const f32x4*)&h2pc[2][c * 20 + g * 4]; \
    h2v_ += *(const f32x4*)&h2pc[3][c * 20 + g * 4]; \
    half4v h2h_, h2l_; \
    _Pragma("unroll") for (int j = 0; j < 4; ++j) { \
      _Float16 h_ = (_Float16)h2v_[j]; \
      h2h_[j] = h_; h2l_[j] = (_Float16)(h2v_[j] - (float)h_); } \
    float qpl_ = 0.f; \
    _Pragma("unroll") for (int mt = 0; mt < 2; ++mt) { \
      half4v pfm_; \
      _Pragma("unroll") for (int j = 0; j < 4; ++j) pfm_[j] = pfx##BI[mt * 4 + j]; \
      f32x4 zz_ = {0, 0, 0, 0}; \
      f32x4 mh_ = MFMA16(pfm_, h2h_, zz_); \
      f32x4 mlv_ = MFMA16(pfm_, h2l_, zz_); \
      f32x4 dd_ = cv##BI[mt] - (mh_ + mlv_); \
      f32x4 mf_ = MV[mt] + dd_; \
      f32x4 zf_ = mf_ + zq##BI[mt]; \
      _Pragma("unroll") for (int r = 0; r < 4; ++r) qpl_ += dd_[r] * dd_[r] * QIV[mt][r]; \
      *(f32x4*)(zf_p + mt * 64) = zf_; \
      zreg[mt] = zf_; \
      half4v zh4_; \
      _Pragma("unroll") for (int r = 0; r < 4; ++r) zh4_[r] = (_Float16)zf_[r]; \
      int row_ = wvc * 4 + mt * 2 + (g >> 1); \
      int base_ = row_ * 128 + (((c + row_) & 15) << 3) + ((g & 1) << 2); \
      *(half4v*)&svhc[base_] = zh4_; \
      f32x4 ms_ = mf_; \
      _Pragma("unroll") for (int r = 0; r < 4; ++r) { \
        float x_ = ms_[r]; \
        x_ += __shfl_xor(x_, 1); x_ += __shfl_xor(x_, 2); \
        x_ += __shfl_xor(x_, 4); x_ += __shfl_xor(x_, 8); \
        ms_[r] = x_ * 0.0625f; } \
      if (c == 0) *(f32x4*)(mf_p + mt * 64) = ms_; \
    } \
    zf_p += 512; mf_p += 512; \
    qpl_ += __shfl_xor(qpl_, 16); \
    qpl_ += __shfl_xor(qpl_, 32); \
    if (g == 0) qppc[BI][wvc * 16 + c] = qpl_; \
  } while (0)

#define PHASE_B(BI, QIV) do { \
    half8v hf_[8]; \
    _Pragma("unroll") for (int kt = 0; kt < 8; ++kt) { \
      int row_ = kt * 4 + g; \
      hf_[kt] = *(const half8v*)&hbc[row_ * 128 + (((c + row_) & 15) << 3)]; } \
    f32x4 a2a_[2], a2b_[2]; \
    _Pragma("unroll") for (int mt = 0; mt < 2; ++mt) { a2a_[mt] = (f32x4){0,0,0,0}; a2b_[mt] = (f32x4){0,0,0,0}; } \
    _Pragma("unroll") for (int kt = 0; kt < 4; ++kt) \
      _Pragma("unroll") for (int mt = 0; mt < 2; ++mt) { \
        a2a_[mt] = MFMA32(w2f[mt][kt], hf_[kt], a2a_[mt]); \
        a2b_[mt] = MFMA32(w2f[mt][kt + 4], hf_[kt + 4], a2b_[mt]); } \
    f32x4 mv_[2]; \
    _Pragma("unroll") for (int mt = 0; mt < 2; ++mt) { \
      mv_[mt] = zreg[mt] + a2a_[mt] + a2b_[mt]; \
      if (wvc < 2) mv_[mt] += ur##BI[mt]; } \
    EPILOG(BI, QIV, mv_); \
  } while (0)

#define KL_FIN(PBI, TPREV) do { \
    if (ct < 16) { \
      float v_ = qppc[PBI][ct] + qppc[PBI][16 + ct] + qppc[PBI][32 + ct] + qppc[PBI][48 + ct]; \
      v_ += __shfl_xor(v_, 1); v_ += __shfl_xor(v_, 2); \
      v_ += __shfl_xor(v_, 4); v_ += __shfl_xor(v_, 8); \
      if (ct == 0) out_kl[(size_t)b * 256 + (size_t)(TPREV)] = 0.03125f * v_ + kv##PBI; \
    } \
  } while (0)

  // ---------------- t = 0 ----------------
  STAGE(0);
  STAGE(1);
  {
    f32x4 mv0[2];
#pragma unroll
    for (int mt = 0; mt < 2; ++mt) {
      mv0[mt] = *(const f32x4*)&m_init[wvc * 32 + mt * 16 + g * 4];
      if (wvc < 2) mv0[mt] += ur0[mt];
    }
    half4v mh0[2], ml0[2];
#pragma unroll
    for (int kt = 0; kt < 2; ++kt)
#pragma unroll
      for (int j = 0; j < 4; ++j) {
        float x = mv0[kt][j];
        _Float16 h = (_Float16)x;
        mh0[kt][j] = h;
        ml0[kt][j] = (_Float16)(x - (float)h);
      }
    half4v ka0_, ka1_;
    KAH(0, 0, ka0_); KAH(0, 1, ka1_);
    f32x4 hz = {0, 0, 0, 0};
    hz = MFMA16(ka0_, mh0[0], hz); hz = MFMA16(ka1_, mh0[1], hz);
    hz = MFMA16(ka0_, ml0[0], hz); hz = MFMA16(ka1_, ml0[1], hz);
    *(f32x4*)&h2pc[wvc][c * 20 + g * 4] = hz;
    BAR();
    EPILOG(0, qiv0, mv0);
    BAR();
  }

  // ---------------- t = 1..254 (pairs) ----------------
  for (int t = 1; t < 255; t += 2) {
    KL_FIN(0, t - 1);
    STAGE(0);
    PHASE_A(1);
    BAR();
    PHASE_B(1, qiv);
    BAR();
    KL_FIN(1, t);
    STAGE(1);
    PHASE_A(0);
    BAR();
    PHASE_B(0, qiv);
    BAR();
  }
  // ---------------- t = 255 ----------------
  KL_FIN(0, 254);
  PHASE_A(1);
  BAR();
  PHASE_B(1, qiv);
  BAR();
  KL_FIN(1, 255);
}

extern "C" void kernel_launch(void* const* d_in, const int* in_sizes, int n_in,
                              void* d_out, int out_size, void* d_ws, size_t ws_size,
                              hipStream_t stream) {
  (void)in_sizes; (void)n_in; (void)out_size;
  const float* u   = (const float*)d_in[0];
  const float* kk  = (const float*)d_in[1];
  const float* Kg  = (const float*)d_in[2];
  const float* epz = (const float*)d_in[3];
  const float* epw = (const float*)d_in[4];
  const float* W1  = (const float*)d_in[5];
  const float* W2  = (const float*)d_in[6];
  const float* mi  = (const float*)d_in[7];
  const float* Qd  = (const float*)d_in[8];
  const float* Q0d = (const float*)d_in[9];

  float* out_zf = (float*)d_out;                      // (S,B,T,L)
  float* out_mf = out_zf + (size_t)33554432;          // (B,T,L)
  float* out_zp = out_mf + (size_t)2097152;           // (S,B,T,L)
  float* out_kl = out_zp + (size_t)33554432;          // (B,T)

  char* ws = (char*)d_ws;
  size_t off = 0;
  auto take = [&](size_t n) { char* p = ws + off; off += n; return p; };
  float*    Ainv = (float*)take(16777216);
  float*    klc  = (float*)take(65536);
  float*    cgp  = (float*)take(8388608);
  _Float16* pfb  = (_Float16*)take(67108864);
  _Float16* w2h  = (_Float16*)take(65536);
  bool zw = ws_size >= off + 134217728;
  float* zpcb = zw ? (float*)take(134217728) : nullptr;
  bool pk = zw && (ws_size >= off + 67108864);
  _Float16* kab = pk ? (_Float16*)take(67108864) : nullptr;
  bool rfws = ws_size >= off + 134217728;
  _Float16* rfb = rfws ? (_Float16*)take(134217728) : (_Float16*)out_zp;
  int wzp = rfws ? 1 : 0;

  kw2_kernel<<<128, 256, 0, stream>>>(W2, w2h);
  kprep1_kernel<<<4096, 256, 0, stream>>>(Kg, kk, u, Qd, Q0d, Ainv, klc, pfb, cgp);
  kprepR_kernel<<<4096, 256, 0, stream>>>(Kg, w2h, rfb, kab);
  kc_kernel<<<16384, 256, 0, stream>>>(Kg, epz, epw, Qd, Q0d, Ainv, out_zf, out_zp,
                                       zpcb, zw ? 1 : 0, wzp);
  if (pk)       kscan_kernel<true,  true ><<<32, 512, 0, stream>>>(u, Kg, W1, W2, mi, Qd, Q0d, pfb, cgp, rfb, kab, zpcb, klc, out_zf, out_mf, out_kl);
  else if (zw)  kscan_kernel<false, true ><<<32, 512, 0, stream>>>(u, Kg, W1, W2, mi, Qd, Q0d, pfb, cgp, rfb, kab, zpcb, klc, out_zf, out_mf, out_kl);
  else          kscan_kernel<false, false><<<32, 512, 0, stream>>>(u, Kg, W1, W2, mi, Qd, Q0d, pfb, cgp, rfb, kab, zpcb, klc, out_zf, out_mf, out_kl);
  if (!rfws) kzp_kernel<<<2048, 256, 0, stream>>>(epz, Qd, Q0d, out_zp);
}

// Round 7
// 1078.188 us; speedup vs baseline: 2.3659x; 2.3659x over previous
//
#include <hip/hip_runtime.h>
#include <cstddef>

typedef _Float16 half8v __attribute__((ext_vector_type(8)));
typedef _Float16 half4v __attribute__((ext_vector_type(4)));
typedef float f32x4 __attribute__((ext_vector_type(4)));

#define MFMA32(A, B, C) __builtin_amdgcn_mfma_f32_16x16x32_f16(A, B, C, 0, 0, 0)
#define MFMA16(A, B, C) __builtin_amdgcn_mfma_f32_16x16x16f16(A, B, C, 0, 0, 0)

// ============ kw2: W2 -> f16 copy (row-major 256x128) ============
__global__ void kw2_kernel(const float* __restrict__ W2, _Float16* __restrict__ w2h) {
  int i = blockIdx.x * 256 + threadIdx.x;
  w2h[i] = (_Float16)W2[i];
}

// ============ kprep1: per (b,t): A, chol (in-wave), Ainv, klc, pf-chunk(f16), c' ============
__global__ void kprep1_kernel(const float* __restrict__ Kg,
                              const float* __restrict__ kg,
                              const float* __restrict__ ug,
                              const float* __restrict__ Qd,
                              const float* __restrict__ Q0d,
                              float* __restrict__ Ainv,
                              float* __restrict__ klc,
                              _Float16* __restrict__ pfb,
                              float* __restrict__ cgp) {
  int tid = threadIdx.x;
  int wv = tid >> 6, ln = tid & 63;
  size_t bt = (size_t)blockIdx.x * 4 + wv;
  int t = (int)(bt & 255);
  __shared__ float Ks[4][128][20];   // later reused as Ps[l][r]
  __shared__ float qs[4][128];
  __shared__ float vvs[4][128];
  __shared__ float Asm[4][16][20];
  __shared__ float LiL[4][16][20];
  __shared__ float AiS[4][16][20];
  __shared__ float yps[4][4][16];
  __shared__ float yvs[4][16];

  const float* kp = Kg + bt * 2048;
  for (int i = ln; i < 2048; i += 64) Ks[wv][i >> 4][i & 15] = kp[i];
  for (int l = ln; l < 128; l += 64) {
    float q = (t == 0) ? Q0d[l] : Qd[l];
    qs[wv][l] = q;
    float v = Qd[l] * kg[bt * 128 + l];
    if (t > 0 && l < 64) v += ug[bt * 64 + l];
    vvs[wv][l] = v;
  }
  __syncthreads();
  {
    int r = ln & 15, c0 = (ln >> 4) << 2;
    float a0 = 0, a1 = 0, a2 = 0, a3 = 0;
    for (int l = 0; l < 128; ++l) {
      float kq = Ks[wv][l][r] * qs[wv][l];
      const float* row = &Ks[wv][l][c0];
      a0 += kq * row[0]; a1 += kq * row[1]; a2 += kq * row[2]; a3 += kq * row[3];
    }
    Asm[wv][r][c0 + 0] = a0 + ((r == c0 + 0) ? 1.f : 0.f);
    Asm[wv][r][c0 + 1] = a1 + ((r == c0 + 1) ? 1.f : 0.f);
    Asm[wv][r][c0 + 2] = a2 + ((r == c0 + 2) ? 1.f : 0.f);
    Asm[wv][r][c0 + 3] = a3 + ((r == c0 + 3) ? 1.f : 0.f);
  }
  {
    int r = ln & 15, seg = ln >> 4;
    float s = 0.f;
    for (int l = seg * 32; l < seg * 32 + 32; ++l) s += Ks[wv][l][r] * vvs[wv][l];
    yps[wv][seg][r] = s;
  }
  __syncthreads();
  if (ln < 16) {
    int i = ln;
    float ar[16], Lr[16];
#pragma unroll
    for (int j = 0; j < 16; ++j) ar[j] = Asm[wv][i][j];
    float ld = 0.f;
#pragma unroll
    for (int j = 0; j < 16; ++j) {
      float ajj = __shfl(ar[j], j, 64);
      float d = sqrtf(ajj);
      ld += __logf(d);
      float li = ar[j] / d;
      li = (i >= j) ? li : 0.f;
      Lr[j] = li;
#pragma unroll
      for (int k2 = j; k2 < 16; ++k2) {
        float lk = __shfl(li, k2, 64);
        ar[k2] -= li * lk;
      }
    }
    int cc = i;
    float Lic[16];
#pragma unroll
    for (int ii = 0; ii < 16; ++ii) {
      float s = (ii == cc) ? 1.f : 0.f;
#pragma unroll
      for (int p = 0; p < 16; ++p) {
        if (p < ii) {
          float Lip = __shfl(Lr[p], ii, 64);
          s -= Lip * Lic[p];
        }
      }
      float dii = __shfl(Lr[ii], ii, 64);
      float v = s / dii;
      Lic[ii] = (ii >= cc) ? v : 0.f;
    }
    float tr = 0.f;
#pragma unroll
    for (int ii = 0; ii < 16; ++ii) { tr += Lic[ii] * Lic[ii]; LiL[wv][cc][ii] = Lic[ii]; }
    tr += __shfl_xor(tr, 1); tr += __shfl_xor(tr, 2);
    tr += __shfl_xor(tr, 4); tr += __shfl_xor(tr, 8);
    if (cc == 0) klc[bt] = 0.5f * (tr - 16.f + 2.f * ld);
    yvs[wv][cc] = yps[wv][0][cc] + yps[wv][1][cc] + yps[wv][2][cc] + yps[wv][3][cc];
  }
  __syncthreads();
  {
    int r = ln & 15, c0 = (ln >> 4) << 2;
    float a0 = 0, a1 = 0, a2 = 0, a3 = 0;
    for (int ii = 0; ii < 16; ++ii) {
      float lir = LiL[wv][r][ii];
      a0 += lir * LiL[wv][c0 + 0][ii];
      a1 += lir * LiL[wv][c0 + 1][ii];
      a2 += lir * LiL[wv][c0 + 2][ii];
      a3 += lir * LiL[wv][c0 + 3][ii];
    }
    AiS[wv][r][c0 + 0] = a0; AiS[wv][r][c0 + 1] = a1;
    AiS[wv][r][c0 + 2] = a2; AiS[wv][r][c0 + 3] = a3;
    f32x4 av = {a0, a1, a2, a3};
    *(f32x4*)&Ainv[bt * 256 + r * 16 + c0] = av;
  }
  __syncthreads();
  // P = q*(K Ainv); c' = q*k - P.y2; store P into Ks (reuse) for fragment gather
  {
#pragma unroll
    for (int li = 0; li < 2; ++li) {
      int l = ln * 2 + li;
      f32x4 acc0 = {0,0,0,0}, acc1v = {0,0,0,0}, acc2v = {0,0,0,0}, acc3v = {0,0,0,0};
      for (int j = 0; j < 16; ++j) {
        float kj = Ks[wv][l][j];
        acc0  += kj * *(const f32x4*)&AiS[wv][j][0];
        acc1v += kj * *(const f32x4*)&AiS[wv][j][4];
        acc2v += kj * *(const f32x4*)&AiS[wv][j][8];
        acc3v += kj * *(const f32x4*)&AiS[wv][j][12];
      }
      float ql = qs[wv][l];
      float cp = ql * kg[bt * 128 + l];
      float pv[16];
#pragma unroll
      for (int e = 0; e < 4; ++e) {
        pv[e] = ql * acc0[e]; pv[4 + e] = ql * acc1v[e];
        pv[8 + e] = ql * acc2v[e]; pv[12 + e] = ql * acc3v[e];
      }
#pragma unroll
      for (int r = 0; r < 16; ++r) cp -= pv[r] * yvs[wv][r];
      cgp[bt * 128 + l] = cp;
#pragma unroll
      for (int r = 0; r < 16; ++r) Ks[wv][l][r] = pv[r];
    }
  }
  __syncthreads();
  {
    int gp = ln >> 4, cp = ln & 15;
#pragma unroll
    for (int ci = 0; ci < 4; ++ci) {
      half8v o;
#pragma unroll
      for (int mt = 0; mt < 2; ++mt)
#pragma unroll
        for (int j = 0; j < 4; ++j)
          o[mt * 4 + j] = (_Float16)Ks[wv][ci * 32 + mt * 16 + cp][gp * 4 + j];
      *(half8v*)(pfb + bt * 2048 + (size_t)(ci * 64 + ln) * 8) = o;
    }
  }
}

// ============ kprepR: R = (W2 K) fragments + K f16 fragments ============
__global__ void kprepR_kernel(const float* __restrict__ Kg,
                              const _Float16* __restrict__ w2h,
                              _Float16* __restrict__ rfb,
                              _Float16* __restrict__ kab) {
  int tid = threadIdx.x;
  int wv = tid >> 6, ln = tid & 63;
  int g = ln >> 4, c = ln & 15;
  __shared__ _Float16 Kh[128][20];
  __shared__ _Float16 Rh[16][264];
  for (int it = 0; it < 4; ++it) {
    size_t bt = (size_t)blockIdx.x * 4 + it;
    const float* kp = Kg + bt * 2048;
    for (int i = tid; i < 2048; i += 256) Kh[i >> 4][i & 15] = (_Float16)kp[i];
    __syncthreads();
    half8v kA[4];
#pragma unroll
    for (int kt = 0; kt < 4; ++kt)
#pragma unroll
      for (int j = 0; j < 8; ++j) kA[kt][j] = Kh[kt * 32 + g * 8 + j][c];
#pragma unroll
    for (int i = 0; i < 4; ++i) {
      int tile = wv * 4 + i;
      f32x4 acc = {0, 0, 0, 0};
#pragma unroll
      for (int kt = 0; kt < 4; ++kt) {
        half8v bf = *(const half8v*)&w2h[(size_t)(tile * 16 + c) * 128 + kt * 32 + g * 8];
        acc = MFMA32(kA[kt], bf, acc);
      }
#pragma unroll
      for (int r = 0; r < 4; ++r) Rh[g * 4 + r][tile * 16 + c] = (_Float16)acc[r];
    }
    __syncthreads();
    half8v r0, r1;
#pragma unroll
    for (int mt = 0; mt < 4; ++mt)
#pragma unroll
      for (int j = 0; j < 4; ++j) {
        _Float16 v = Rh[c][wv * 64 + mt * 16 + g * 4 + j];
        if (mt < 2) r0[mt * 4 + j] = v; else r1[(mt - 2) * 4 + j] = v;
      }
    *(half8v*)(rfb + bt * 4096 + (size_t)tid * 16) = r0;
    *(half8v*)(rfb + bt * 4096 + (size_t)tid * 16 + 8) = r1;
    if (kab) {
      half8v ko;
#pragma unroll
      for (int kt = 0; kt < 2; ++kt)
#pragma unroll
        for (int j = 0; j < 4; ++j) ko[kt * 4 + j] = Kh[wv * 32 + kt * 16 + g * 4 + j][c];
      *(half8v*)(kab + bt * 2048 + (size_t)tid * 8) = ko;
    }
    __syncthreads();
  }
}

// ============ kc: per (t,b): z_p out + zpc = z_p - K Ainv (K^T z_p + ew) ============
__global__ void kc_kernel(const float* __restrict__ Kg,
                          const float* __restrict__ epsz,
                          const float* __restrict__ epsw,
                          const float* __restrict__ Qd,
                          const float* __restrict__ Q0d,
                          const float* __restrict__ Ainv,
                          float* __restrict__ out_zf,
                          float* __restrict__ out_zp,
                          float* __restrict__ zpcb,
                          int zw, int wzp) {
  int idx = blockIdx.x;
  int t = idx >> 6, b = idx & 63;
  int bt = b * 256 + t;
  __shared__ float Ks[128][16];
  __shared__ float Ai[16][16];
  __shared__ float zp[16][129];
  __shared__ float hh[16][17];
  __shared__ float ww[16][17];
  __shared__ float sq[128];
  const float* kp = Kg + (size_t)bt * 2048;
  for (int i = threadIdx.x; i < 2048; i += 256) ((float*)Ks)[i] = kp[i];
  ((float*)Ai)[threadIdx.x] = Ainv[(size_t)bt * 256 + threadIdx.x];
  const float* q = (t == 0) ? Q0d : Qd;
  if (threadIdx.x < 128) sq[threadIdx.x] = sqrtf(q[threadIdx.x]);
  __syncthreads();
  for (int i = threadIdx.x; i < 2048; i += 256) {
    int s = i >> 7, l = i & 127;
    float v = sq[l] * epsz[(((size_t)t * 16 + s) * 64 + b) * 128 + l];
    zp[s][l] = v;
    if (wzp) out_zp[(((size_t)s * 64 + b) * 256 + t) * 128 + l] = v;
  }
  __syncthreads();
  {
    int s = threadIdx.x >> 4, r = threadIdx.x & 15;
    float acc = epsw[(((size_t)t * 16 + s) * 64 + b) * 16 + r];
    for (int l = 0; l < 128; ++l) acc += Ks[l][r] * zp[s][l];
    hh[s][r] = acc;
  }
  __syncthreads();
  {
    int s = threadIdx.x >> 4, r = threadIdx.x & 15;
    float acc = 0.f;
    for (int j = 0; j < 16; ++j) acc += Ai[r][j] * hh[s][j];
    ww[s][r] = acc;
  }
  __syncthreads();
  for (int i = threadIdx.x; i < 2048; i += 256) {
    int s = i >> 7, l = i & 127;
    float acc = 0.f;
    for (int r = 0; r < 16; ++r) acc += Ks[l][r] * ww[s][r];
    float v = zp[s][l] - acc;
    if (zw) zpcb[(size_t)bt * 2048 + i] = v;
    else out_zf[(((size_t)s * 64 + b) * 256 + t) * 128 + l] = v;
  }
}

// ============ kzp: rebuild out_zp after kscan (rf lived in out_zp) ============
__global__ void kzp_kernel(const float* __restrict__ epsz,
                           const float* __restrict__ Qd,
                           const float* __restrict__ Q0d,
                           float* __restrict__ out_zp) {
  for (size_t i = (size_t)blockIdx.x * blockDim.x + threadIdx.x; i < (size_t)33554432;
       i += (size_t)gridDim.x * blockDim.x) {
    int l = (int)(i & 127);
    int t = (int)((i >> 7) & 255);
    int sb = (int)(i >> 15);
    int s = sb >> 6, b = sb & 63;
    float q = (t == 0) ? Q0d[l] : Qd[l];
    out_zp[i] = sqrtf(q) * epsz[(((size_t)t * 16 + s) * 64 + b) * 128 + l];
  }
}

// raw barrier: LDS-only drain, global loads/stores stay in flight
#define BAR() asm volatile("s_waitcnt lgkmcnt(0)\n\ts_barrier" ::: "memory")

// ============ shared scan body: one chain = 256 threads (ct in [0,256)) ============
template <bool PK, bool ZW>
__device__ __forceinline__ void scan_body(
    const int b, const int ct,
    _Float16* __restrict__ svhc, _Float16* __restrict__ hbc,
    float (*__restrict__ h2pc)[320], float (*__restrict__ qppc)[64],
    const float* __restrict__ ug, const float* __restrict__ Kg,
    const float* __restrict__ W1, const float* __restrict__ W2,
    const float* __restrict__ m_init, const float* __restrict__ Qd,
    const float* __restrict__ Q0d, const _Float16* __restrict__ pfb,
    const float* __restrict__ cgp, const _Float16* __restrict__ rfb,
    const _Float16* __restrict__ kab, const float* __restrict__ zpcb,
    const float* __restrict__ klcp, float* __restrict__ out_zf,
    float* __restrict__ out_mf, float* __restrict__ out_kl) {
  const int wvc = ct >> 6;        // dim-split wave within chain
  const int ln = ct & 63;         // lane (ct ≡ tid mod 256, 64 | 256)
  const int g = ln >> 4;
  const int c = ln & 15;

  half8v w1f[4][4];
#pragma unroll
  for (int mt = 0; mt < 4; ++mt)
#pragma unroll
    for (int kt = 0; kt < 4; ++kt) {
      half8v v;
#pragma unroll
      for (int j = 0; j < 8; ++j)
        v[j] = (_Float16)W1[(size_t)(kt * 32 + g * 8 + j) * 256 + (wvc * 64 + mt * 16 + c)];
      w1f[mt][kt] = v;
    }
  half8v w2f[2][8];
#pragma unroll
  for (int mt = 0; mt < 2; ++mt)
#pragma unroll
    for (int kt = 0; kt < 8; ++kt) {
      half8v v;
#pragma unroll
      for (int j = 0; j < 8; ++j)
        v[j] = (_Float16)W2[(size_t)(kt * 32 + g * 8 + j) * 128 + (wvc * 32 + mt * 16 + c)];
      w2f[mt][kt] = v;
    }

  f32x4 qiv[2], qiv0[2];
#pragma unroll
  for (int mt = 0; mt < 2; ++mt) {
    f32x4 q = *(const f32x4*)&Qd[wvc * 32 + mt * 16 + g * 4];
    f32x4 q0 = *(const f32x4*)&Q0d[wvc * 32 + mt * 16 + g * 4];
#pragma unroll
    for (int r = 0; r < 4; ++r) { qiv[mt][r] = 1.f / q[r]; qiv0[mt][r] = 1.f / q0[r]; }
  }

  f32x4 zreg[2];

  half8v pfx0, pfx1, kax0 = {}, kax1 = {}, rfa0, rfa1, rfc0, rfc1;
  float kf0[8], kf1[8];
  f32x4 zq0[2], zq1[2], cv0[2], cv1[2];
  f32x4 ur0[2] = {}, ur1[2] = {};
  float kv0 = 0.f, kv1 = 0.f;

  const char* pf_p = (const char*)pfb + (size_t)b * 256 * 4096 + (size_t)ct * 16;
  const char* ka_p = PK ? (const char*)kab + (size_t)b * 256 * 4096 + (size_t)ct * 16
                        : (const char*)pfb;
  const char* K_p = (const char*)Kg + (size_t)b * 256 * 8192 + (size_t)((wvc * 32 + g * 4) * 16 + c) * 4;
  const char* rf_p = (const char*)rfb + (size_t)b * 256 * 8192 + (size_t)ct * 32;
  const char* zq_p = ZW ? (const char*)zpcb + (size_t)b * 256 * 8192 + (size_t)(c * 128 + wvc * 32 + g * 4) * 4
                        : (const char*)out_zf + ((((size_t)c * 64 + b) * 256) * 128 + wvc * 32 + g * 4) * 4;
  const size_t zq_str = ZW ? 8192 : 512;
  const char* cv_p = (const char*)cgp + (size_t)b * 256 * 512 + (size_t)(wvc * 32 + g * 4) * 4;
  const char* ur_p = (const char*)ug + (size_t)b * 256 * 256 + (size_t)(wvc * 32 + g * 4) * 4;
  const char* kl_p = (const char*)klcp + (size_t)b * 256 * 4;
  char* zf_p = (char*)out_zf + ((((size_t)c * 64 + b) * 256) * 128 + wvc * 32 + g * 4) * 4;
  char* mf_p = (char*)out_mf + ((size_t)b * 256 * 128 + wvc * 32 + g * 4) * 4;

#define STAGE(BI) do { \
    pfx##BI = *(const half8v*)pf_p; pf_p += 4096; \
    if constexpr (PK) { kax##BI = *(const half8v*)ka_p; ka_p += 4096; } \
    else { _Pragma("unroll") for (int kt_ = 0; kt_ < 2; ++kt_) \
             _Pragma("unroll") for (int j_ = 0; j_ < 4; ++j_) \
               kf##BI[kt_ * 4 + j_] = *(const float*)(K_p + kt_ * 1024 + j_ * 64); \
           K_p += 8192; } \
    rfa##BI = *(const half8v*)rf_p; rfc##BI = *(const half8v*)(rf_p + 16); rf_p += 8192; \
    zq##BI[0] = *(const f32x4*)zq_p; zq##BI[1] = *(const f32x4*)(zq_p + 64); zq_p += zq_str; \
    cv##BI[0] = *(const f32x4*)cv_p; cv##BI[1] = *(const f32x4*)(cv_p + 64); cv_p += 512; \
    if (wvc < 2) { ur##BI[0] = *(const f32x4*)ur_p; ur##BI[1] = *(const f32x4*)(ur_p + 64); } \
    ur_p += 256; \
    kv##BI = *(const float*)kl_p; kl_p += 4; \
  } while (0)

#define KAH(BI, KT, DST) do { \
    if constexpr (PK) { _Pragma("unroll") for (int j_ = 0; j_ < 4; ++j_) DST[j_] = kax##BI[(KT) * 4 + j_]; } \
    else { _Pragma("unroll") for (int j_ = 0; j_ < 4; ++j_) DST[j_] = (_Float16)kf##BI[(KT) * 4 + j_]; } \
  } while (0)

#define PHASE_A(BI) do { \
    half4v zbh_[2], zbl_[2]; \
    _Pragma("unroll") for (int kt = 0; kt < 2; ++kt) \
      _Pragma("unroll") for (int j = 0; j < 4; ++j) { \
        float x_ = zreg[kt][j]; _Float16 h_ = (_Float16)x_; \
        zbh_[kt][j] = h_; zbl_[kt][j] = (_Float16)(x_ - (float)h_); } \
    half8v zh8_[4]; \
    _Pragma("unroll") for (int kt = 0; kt < 4; ++kt) { \
      int row_ = kt * 4 + g; \
      int idx_ = row_ * 128 + (((c + row_) & 15) << 3); \
      zh8_[kt] = *(const half8v*)&svhc[idx_]; } \
    f32x4 a1h_[4]; \
    _Pragma("unroll") for (int mt = 0; mt < 4; ++mt) a1h_[mt] = (f32x4){0,0,0,0}; \
    _Pragma("unroll") for (int kt = 0; kt < 4; ++kt) \
      _Pragma("unroll") for (int mt = 0; mt < 4; ++mt) \
        a1h_[mt] = MFMA32(w1f[mt][kt], zh8_[kt], a1h_[mt]); \
    half4v th_[4]; \
    _Pragma("unroll") for (int mt = 0; mt < 4; ++mt) { \
      _Pragma("unroll") for (int r = 0; r < 4; ++r) { \
        float x_ = a1h_[mt][r]; \
        float e_ = __expf(2.f * x_); \
        th_[mt][r] = (_Float16)(1.f - 2.f / (e_ + 1.f)); } \
      int row_ = wvc * 8 + mt * 2 + (g >> 1); \
      *(half4v*)&hbc[row_ * 128 + (((c + row_) & 15) << 3) + ((g & 1) << 2)] = th_[mt]; } \
    half4v ka0_, ka1_; KAH(BI, 0, ka0_); KAH(BI, 1, ka1_); \
    f32x4 hz_ = {0, 0, 0, 0}; \
    hz_ = MFMA16(ka0_, zbh_[0], hz_); hz_ = MFMA16(ka1_, zbh_[1], hz_); \
    hz_ = MFMA16(ka0_, zbl_[0], hz_); hz_ = MFMA16(ka1_, zbl_[1], hz_); \
    f32x4 hr_ = {0, 0, 0, 0}; \
    _Pragma("unroll") for (int mt = 0; mt < 4; ++mt) { \
      half4v rr_; \
      _Pragma("unroll") for (int j = 0; j < 4; ++j) \
        rr_[j] = (mt < 2) ? rfa##BI[mt * 4 + j] : rfc##BI[(mt - 2) * 4 + j]; \
      hr_ = MFMA16(rr_, th_[mt], hr_); } \
    *(f32x4*)&h2pc[wvc][c * 20 + g * 4] = hz_ + hr_; \
  } while (0)

#define EPILOG(BI, QIV, MV) do { \
    f32x4 h2v_ = *(const f32x4*)&h2pc[0][c * 20 + g * 4]; \
    h2v_ += *(const f32x4*)&h2pc[1][c * 20 + g * 4]; \
    h2v_ += *(const f32x4*)&h2pc[2][c * 20 + g * 4]; \
    h2v_ += *(const f32x4*)&h2pc[3][c * 20 + g * 4]; \
    half4v h2h_, h2l_; \
    _Pragma("unroll") for (int j = 0; j < 4; ++j) { \
      _Float16 h_ = (_Float16)h2v_[j]; \
      h2h_[j] = h_; h2l_[j] = (_Float16)(h2v_[j] - (float)h_); } \
    float qpl_ = 0.f; \
    _Pragma("unroll") for (int mt = 0; mt < 2; ++mt) { \
      half4v pfm_; \
      _Pragma("unroll") for (int j = 0; j < 4; ++j) pfm_[j] = pfx##BI[mt * 4 + j]; \
      f32x4 zz_ = {0, 0, 0, 0}; \
      f32x4 mh_ = MFMA16(pfm_, h2h_, zz_); \
      f32x4 mlv_ = MFMA16(pfm_, h2l_, zz_); \
      f32x4 dd_ = cv##BI[mt] - (mh_ + mlv_); \
      f32x4 mf_ = MV[mt] + dd_; \
      f32x4 zf_ = mf_ + zq##BI[mt]; \
      _Pragma("unroll") for (int r = 0; r < 4; ++r) qpl_ += dd_[r] * dd_[r] * QIV[mt][r]; \
      *(f32x4*)(zf_p + mt * 64) = zf_; \
      zreg[mt] = zf_; \
      half4v zh4_; \
      _Pragma("unroll") for (int r = 0; r < 4; ++r) zh4_[r] = (_Float16)zf_[r]; \
      int row_ = wvc * 4 + mt * 2 + (g >> 1); \
      int base_ = row_ * 128 + (((c + row_) & 15) << 3) + ((g & 1) << 2); \
      *(half4v*)&svhc[base_] = zh4_; \
      f32x4 ms_ = mf_; \
      _Pragma("unroll") for (int r = 0; r < 4; ++r) { \
        float x_ = ms_[r]; \
        x_ += __shfl_xor(x_, 1); x_ += __shfl_xor(x_, 2); \
        x_ += __shfl_xor(x_, 4); x_ += __shfl_xor(x_, 8); \
        ms_[r] = x_ * 0.0625f; } \
      if (c == 0) *(f32x4*)(mf_p + mt * 64) = ms_; \
    } \
    zf_p += 512; mf_p += 512; \
    qpl_ += __shfl_xor(qpl_, 16); \
    qpl_ += __shfl_xor(qpl_, 32); \
    if (g == 0) qppc[BI][wvc * 16 + c] = qpl_; \
  } while (0)

#define PHASE_B(BI, QIV) do { \
    half8v hf_[8]; \
    _Pragma("unroll") for (int kt = 0; kt < 8; ++kt) { \
      int row_ = kt * 4 + g; \
      hf_[kt] = *(const half8v*)&hbc[row_ * 128 + (((c + row_) & 15) << 3)]; } \
    f32x4 a2a_[2], a2b_[2]; \
    _Pragma("unroll") for (int mt = 0; mt < 2; ++mt) { a2a_[mt] = (f32x4){0,0,0,0}; a2b_[mt] = (f32x4){0,0,0,0}; } \
    _Pragma("unroll") for (int kt = 0; kt < 4; ++kt) \
      _Pragma("unroll") for (int mt = 0; mt < 2; ++mt) { \
        a2a_[mt] = MFMA32(w2f[mt][kt], hf_[kt], a2a_[mt]); \
        a2b_[mt] = MFMA32(w2f[mt][kt + 4], hf_[kt + 4], a2b_[mt]); } \
    f32x4 mv_[2]; \
    _Pragma("unroll") for (int mt = 0; mt < 2; ++mt) { \
      mv_[mt] = zreg[mt] + a2a_[mt] + a2b_[mt]; \
      if (wvc < 2) mv_[mt] += ur##BI[mt]; } \
    EPILOG(BI, QIV, mv_); \
  } while (0)

#define KL_FIN(PBI, TPREV) do { \
    if (ct < 16) { \
      float v_ = qppc[PBI][ct] + qppc[PBI][16 + ct] + qppc[PBI][32 + ct] + qppc[PBI][48 + ct]; \
      v_ += __shfl_xor(v_, 1); v_ += __shfl_xor(v_, 2); \
      v_ += __shfl_xor(v_, 4); v_ += __shfl_xor(v_, 8); \
      if (ct == 0) out_kl[(size_t)b * 256 + (size_t)(TPREV)] = 0.03125f * v_ + kv##PBI; \
    } \
  } while (0)

  // ---------------- t = 0 ----------------
  STAGE(0);
  STAGE(1);
  {
    f32x4 mv0[2];
#pragma unroll
    for (int mt = 0; mt < 2; ++mt) {
      mv0[mt] = *(const f32x4*)&m_init[wvc * 32 + mt * 16 + g * 4];
      if (wvc < 2) mv0[mt] += ur0[mt];
    }
    half4v mh0[2], ml0[2];
#pragma unroll
    for (int kt = 0; kt < 2; ++kt)
#pragma unroll
      for (int j = 0; j < 4; ++j) {
        float x = mv0[kt][j];
        _Float16 h = (_Float16)x;
        mh0[kt][j] = h;
        ml0[kt][j] = (_Float16)(x - (float)h);
      }
    half4v ka0_, ka1_;
    KAH(0, 0, ka0_); KAH(0, 1, ka1_);
    f32x4 hz = {0, 0, 0, 0};
    hz = MFMA16(ka0_, mh0[0], hz); hz = MFMA16(ka1_, mh0[1], hz);
    hz = MFMA16(ka0_, ml0[0], hz); hz = MFMA16(ka1_, ml0[1], hz);
    *(f32x4*)&h2pc[wvc][c * 20 + g * 4] = hz;
    BAR();
    EPILOG(0, qiv0, mv0);
    BAR();
  }

  // ---------------- t = 1..254 (pairs) ----------------
  for (int t = 1; t < 255; t += 2) {
    KL_FIN(0, t - 1);
    STAGE(0);
    PHASE_A(1);
    BAR();
    PHASE_B(1, qiv);
    BAR();
    KL_FIN(1, t);
    STAGE(1);
    PHASE_A(0);
    BAR();
    PHASE_B(0, qiv);
    BAR();
  }
  // ---------------- t = 255 ----------------
  KL_FIN(0, 254);
  PHASE_A(1);
  BAR();
  PHASE_B(1, qiv);
  BAR();
  KL_FIN(1, 255);

#undef STAGE
#undef KAH
#undef PHASE_A
#undef EPILOG
#undef PHASE_B
#undef KL_FIN
}

// ============ kscan1: 256 threads, one chain (round-4 proven fallback) ============
template <bool PK, bool ZW>
__launch_bounds__(256, 1)
__global__ void kscan1_kernel(const float* __restrict__ ug, const float* __restrict__ Kg,
                              const float* __restrict__ W1, const float* __restrict__ W2,
                              const float* __restrict__ m_init, const float* __restrict__ Qd,
                              const float* __restrict__ Q0d, const _Float16* __restrict__ pfb,
                              const float* __restrict__ cgp, const _Float16* __restrict__ rfb,
                              const _Float16* __restrict__ kab, const float* __restrict__ zpcb,
                              const float* __restrict__ klcp, float* __restrict__ out_zf,
                              float* __restrict__ out_mf, float* __restrict__ out_kl) {
  __shared__ __align__(16) _Float16 svh[2048];
  __shared__ __align__(16) _Float16 hb[4096];
  __shared__ float h2p[4][320];
  __shared__ float qpp[2][64];
  scan_body<PK, ZW>(blockIdx.x, threadIdx.x, svh, hb, h2p, qpp,
                    ug, Kg, W1, W2, m_init, Qd, Q0d, pfb, cgp, rfb, kab, zpcb, klcp,
                    out_zf, out_mf, out_kl);
}

// ============ kscan2: 512 threads, TWO chains; explicit VGPR contract ============
// amdgpu_waves_per_eu(2,2): allocator budget = 512-reg pool / 2 = 256 VGPRs.
// (round-5/6 lesson: __launch_bounds__ second arg capped us at 128 -> spill).
template <bool PK, bool ZW>
__attribute__((amdgpu_flat_work_group_size(512, 512)))
__attribute__((amdgpu_waves_per_eu(2, 2)))
__global__ void kscan2_kernel(const float* __restrict__ ug, const float* __restrict__ Kg,
                              const float* __restrict__ W1, const float* __restrict__ W2,
                              const float* __restrict__ m_init, const float* __restrict__ Qd,
                              const float* __restrict__ Q0d, const _Float16* __restrict__ pfb,
                              const float* __restrict__ cgp, const _Float16* __restrict__ rfb,
                              const _Float16* __restrict__ kab, const float* __restrict__ zpcb,
                              const float* __restrict__ klcp, float* __restrict__ out_zf,
                              float* __restrict__ out_mf, float* __restrict__ out_kl) {
  __shared__ __align__(16) _Float16 svh[2][2048];
  __shared__ __align__(16) _Float16 hb[2][4096];
  __shared__ float h2p[2][4][320];
  __shared__ float qpp[2][2][64];
  const int ch = threadIdx.x >> 8;
  scan_body<PK, ZW>(blockIdx.x * 2 + ch, threadIdx.x & 255,
                    svh[ch], hb[ch], h2p[ch], qpp[ch],
                    ug, Kg, W1, W2, m_init, Qd, Q0d, pfb, cgp, rfb, kab, zpcb, klcp,
                    out_zf, out_mf, out_kl);
}

extern "C" void kernel_launch(void* const* d_in, const int* in_sizes, int n_in,
                              void* d_out, int out_size, void* d_ws, size_t ws_size,
                              hipStream_t stream) {
  (void)in_sizes; (void)n_in; (void)out_size;
  const float* u   = (const float*)d_in[0];
  const float* kk  = (const float*)d_in[1];
  const float* Kg  = (const float*)d_in[2];
  const float* epz = (const float*)d_in[3];
  const float* epw = (const float*)d_in[4];
  const float* W1  = (const float*)d_in[5];
  const float* W2  = (const float*)d_in[6];
  const float* mi  = (const float*)d_in[7];
  const float* Qd  = (const float*)d_in[8];
  const float* Q0d = (const float*)d_in[9];

  float* out_zf = (float*)d_out;                      // (S,B,T,L)
  float* out_mf = out_zf + (size_t)33554432;          // (B,T,L)
  float* out_zp = out_mf + (size_t)2097152;           // (S,B,T,L)
  float* out_kl = out_zp + (size_t)33554432;          // (B,T)

  char* ws = (char*)d_ws;
  size_t off = 0;
  auto take = [&](size_t n) { char* p = ws + off; off += n; return p; };
  float*    Ainv = (float*)take(16777216);
  float*    klc  = (float*)take(65536);
  float*    cgp  = (float*)take(8388608);
  _Float16* pfb  = (_Float16*)take(67108864);
  _Float16* w2h  = (_Float16*)take(65536);
  bool zw = ws_size >= off + 134217728;
  float* zpcb = zw ? (float*)take(134217728) : nullptr;
  bool pk = zw && (ws_size >= off + 67108864);
  _Float16* kab = pk ? (_Float16*)take(67108864) : nullptr;
  bool rfws = ws_size >= off + 134217728;
  _Float16* rfb = rfws ? (_Float16*)take(134217728) : (_Float16*)out_zp;
  int wzp = rfws ? 1 : 0;

  kw2_kernel<<<128, 256, 0, stream>>>(W2, w2h);
  kprep1_kernel<<<4096, 256, 0, stream>>>(Kg, kk, u, Qd, Q0d, Ainv, klc, pfb, cgp);
  kprepR_kernel<<<4096, 256, 0, stream>>>(Kg, w2h, rfb, kab);
  kc_kernel<<<16384, 256, 0, stream>>>(Kg, epz, epw, Qd, Q0d, Ainv, out_zf, out_zp,
                                       zpcb, zw ? 1 : 0, wzp);

  // guard: only use the 512-thread 2-chain scan if it compiled spill-free
  auto pick = [&](const void* f2) {
    hipFuncAttributes fa;
    if (hipFuncGetAttributes(&fa, f2) == hipSuccess)
      return fa.localSizeBytes == 0 && fa.numRegs > 140;
    return false;
  };
#define LAUNCH_SCAN(PKV, ZWV) do { \
    if (pick((const void*)kscan2_kernel<PKV, ZWV>)) \
      kscan2_kernel<PKV, ZWV><<<32, 512, 0, stream>>>(u, Kg, W1, W2, mi, Qd, Q0d, pfb, cgp, rfb, kab, zpcb, klc, out_zf, out_mf, out_kl); \
    else \
      kscan1_kernel<PKV, ZWV><<<64, 256, 0, stream>>>(u, Kg, W1, W2, mi, Qd, Q0d, pfb, cgp, rfb, kab, zpcb, klc, out_zf, out_mf, out_kl); \
  } while (0)

  if (pk)      LAUNCH_SCAN(true,  true);
  else if (zw) LAUNCH_SCAN(false, true);
  else         LAUNCH_SCAN(false, false);
#undef LAUNCH_SCAN

  if (!rfws) kzp_kernel<<<2048, 256, 0, stream>>>(epz, Qd, Q0d, out_zp);
}